// Round 8
// baseline (464.202 us; speedup 1.0000x reference)
//
#include <hip/hip_runtime.h>

// HyperLayer: y[b, f0/c0] += v * w0 * (wf1*x[b,f1] + wc1*x[b,c1])
// B=16, N=262144, DIM=8192.
// R8: R1-R7 pinned at ~51us under every load/occupancy/atomic-flavor change.
// Remaining suspect: the LDS scatter chain (ds_read2 gather waits behind
// interleaved ds_add_f32 in the in-order lgkmcnt queue -> ~477 exposed
// cyc/wave-iter). Fix: drop y_s entirely; scatter straight to global y with
// no-return unsafeAtomicAdd (fire-and-forget to L2; R1 measured 4.2M hotter
// atomics at ~6us). Gather x from LDS stays, now the only DS op in the loop.
// Also deletes partials traffic (32 MB) and the reduce kernel.

#define BATCH 16
#define NPTS 262144
#define DIM 8192
#define SPLITS 32
#define PTS_PER_BLOCK (NPTS / SPLITS)   // 8192
#define BLOCK 512

__global__ __launch_bounds__(BLOCK, 4) void hyper_scatter_kernel(
    const float* __restrict__ x,    // [B, DIM]
    const float* __restrict__ ri,   // [B, N, 2]
    const float* __restrict__ rv,   // [B, N]
    float* __restrict__ y)          // [B, DIM], pre-zeroed
{
    __shared__ float x_s[DIM];   // 32 KB, read-only after stage

    const int tid   = threadIdx.x;
    const int split = blockIdx.x;
    const int b     = blockIdx.y;

    const float4* x4 = (const float4*)(x + (size_t)b * DIM);
    float4* xs4 = (float4*)x_s;
    #pragma unroll
    for (int i = tid; i < DIM / 4; i += BLOCK) {
        xs4[i] = x4[i];
    }
    __syncthreads();

    const size_t base = (size_t)b * NPTS + (size_t)split * PTS_PER_BLOCK;
    const float2* idx2 = (const float2*)ri + base;
    const float*  val  = rv + base;
    float* yrow = y + (size_t)b * DIM;

    #pragma unroll 4
    for (int i = tid; i < PTS_PER_BLOCK; i += BLOCK) {
        float2 r = idx2[i];
        float v  = val[i];

        float f0 = floorf(r.x), c0 = ceilf(r.x);
        float f1 = floorf(r.y), c1 = ceilf(r.y);
        // Per reference: w = 1 - |corner - real|, floor/ceil independently
        // (both corners get weight 1 when floor==ceil -> double count).
        float wf0 = 1.0f - (r.x - f0), wc0 = 1.0f - (c0 - r.x);
        float wf1 = 1.0f - (r.y - f1), wc1 = 1.0f - (c1 - r.y);

        // Paired gather at {f1, f1+1}; integral r.y -> second operand is x[f1].
        int i1 = (int)f1;
        float xa = x_s[i1];
        float xb = x_s[i1 + 1];          // in range: f1 <= 8182
        xb = (c1 == f1) ? xa : xb;

        float gx = wf1 * xa + wc1 * xb;
        float vg = v * gx;
        // Fire-and-forget device-scope fp32 atomics into L2 (no return,
        // no lgkmcnt involvement -> gather chain stays clean).
        unsafeAtomicAdd(&yrow[(int)f0], wf0 * vg);
        unsafeAtomicAdd(&yrow[(int)c0], wc0 * vg);
    }
}

extern "C" void kernel_launch(void* const* d_in, const int* in_sizes, int n_in,
                              void* d_out, int out_size, void* d_ws, size_t ws_size,
                              hipStream_t stream) {
    const float* x  = (const float*)d_in[0];
    const float* ri = (const float*)d_in[1];
    const float* rv = (const float*)d_in[2];
    float* y = (float*)d_out;

    // y is accumulated via atomics; harness poisons it before every launch.
    hipMemsetAsync(y, 0, (size_t)out_size * sizeof(float), stream);

    dim3 grid(SPLITS, BATCH);
    hyper_scatter_kernel<<<grid, BLOCK, 0, stream>>>(x, ri, rv, y);
}

// Round 10
// 128.342 us; speedup vs baseline: 3.6169x; 3.6169x over previous
//
#include <hip/hip_runtime.h>

// HyperLayer: y[b, f0/c0] += v * w0 * (wf1*x[b,f1] + wc1*x[b,c1])
// B=16, N=262144, DIM=8192.
// R10: discrimination experiment. Elimination (R3-R8) left the LDS pipe as
// the wall: 65.5K scattered lane-accesses/CU at ~1.9 cyc each = 51us.
// This round moves the x-gather from LDS to L1 (32KB row is L1-resident;
// VMEM pipe is idle), leaving LDS only the 2 scatter-atomics per point.
// Uniform-LDS-wall theory predicts ~27-32us; atomic-only-wall predicts no
// change. Exotic asm from R9 reverted (issue/wait split across asm blocks
// is unsound - regalloc copies un-landed results).

#define BATCH 16
#define NPTS 262144
#define DIM 8192
#define SPLITS 32
#define PTS_PER_BLOCK (NPTS / SPLITS)   // 8192
#define BLOCK 512

__global__ __launch_bounds__(BLOCK, 4) void hyper_scatter_kernel(
    const float* __restrict__ x,    // [B, DIM]
    const float* __restrict__ ri,   // [B, N, 2]
    const float* __restrict__ rv,   // [B, N]
    float* __restrict__ partials)   // [B*SPLITS, DIM]
{
    __shared__ float y_s[DIM];   // 32 KB accumulator; no x staging this round

    const int tid   = threadIdx.x;
    const int split = blockIdx.x;
    const int b     = blockIdx.y;

    float4* ys4 = (float4*)y_s;
    #pragma unroll
    for (int i = tid; i < DIM / 4; i += BLOCK) {
        ys4[i] = make_float4(0.f, 0.f, 0.f, 0.f);
    }
    __syncthreads();

    const float* xrow = x + (size_t)b * DIM;   // gathered via L1/L2
    const size_t base = (size_t)b * NPTS + (size_t)split * PTS_PER_BLOCK;
    const float2* idx2 = (const float2*)ri + base;
    const float*  val  = rv + base;

    #pragma unroll 4
    for (int i = tid; i < PTS_PER_BLOCK; i += BLOCK) {
        float2 r = idx2[i];
        float v  = val[i];

        float f0 = floorf(r.x), c0 = ceilf(r.x);
        float f1 = floorf(r.y), c1 = ceilf(r.y);
        // Per reference: w = 1 - |corner - real|, floor/ceil independently
        // (both corners get weight 1 when floor==ceil -> double count).
        float wf0 = 1.0f - (r.x - f0), wc0 = 1.0f - (c0 - r.x);
        float wf1 = 1.0f - (r.y - f1), wc1 = 1.0f - (c1 - r.y);

        // Gather from global (L1-resident 32KB row) - VMEM pipe, not LDS.
        float xa = xrow[(int)f1];
        float xb = xrow[(int)c1];

        float vg = v * (wf1 * xa + wc1 * xb);
        unsafeAtomicAdd(&y_s[(int)f0], wf0 * vg);   // native ds_add_f32
        unsafeAtomicAdd(&y_s[(int)c0], wc0 * vg);
    }
    __syncthreads();

    // Coalesced float4 store of the partial row (no atomics).
    float4* out4 = (float4*)(partials + ((size_t)b * SPLITS + split) * DIM);
    #pragma unroll
    for (int i = tid; i < DIM / 4; i += BLOCK) {
        out4[i] = ys4[i];
    }
}

// y[b][d] = sum_s partials[b*SPLITS+s][d]; one float4 per thread.
__global__ __launch_bounds__(256) void reduce_partials_kernel(
    const float* __restrict__ partials, float* __restrict__ y)
{
    const int d4 = blockIdx.x * 256 + threadIdx.x;      // [0, B*DIM/4)
    const int b   = d4 / (DIM / 4);
    const int off = d4 % (DIM / 4);
    const float4* p = (const float4*)(partials + (size_t)b * SPLITS * DIM) + off;
    float4 acc = make_float4(0.f, 0.f, 0.f, 0.f);
    #pragma unroll
    for (int s = 0; s < SPLITS; ++s) {
        float4 v = p[(size_t)s * (DIM / 4)];
        acc.x += v.x; acc.y += v.y; acc.z += v.z; acc.w += v.w;
    }
    ((float4*)y)[d4] = acc;
}

// Fallback (ws too small): LDS-accumulate + global-atomic flush.
__global__ __launch_bounds__(BLOCK, 4) void hyper_scatter_atomic_kernel(
    const float* __restrict__ x, const float* __restrict__ ri,
    const float* __restrict__ rv, float* __restrict__ y)
{
    __shared__ float y_s[DIM];
    const int tid = threadIdx.x, split = blockIdx.x, b = blockIdx.y;
    float4* ys4 = (float4*)y_s;
    for (int i = tid; i < DIM / 4; i += BLOCK) {
        ys4[i] = make_float4(0.f, 0.f, 0.f, 0.f);
    }
    __syncthreads();
    const float* xrow = x + (size_t)b * DIM;
    const size_t base = (size_t)b * NPTS + (size_t)split * PTS_PER_BLOCK;
    const float2* idx2 = (const float2*)ri + base;
    const float*  val  = rv + base;
    for (int i = tid; i < PTS_PER_BLOCK; i += BLOCK) {
        float2 r = idx2[i];
        float v  = val[i];
        float f0 = floorf(r.x), c0 = ceilf(r.x);
        float f1 = floorf(r.y), c1 = ceilf(r.y);
        float wf0 = 1.0f - (r.x - f0), wc0 = 1.0f - (c0 - r.x);
        float wf1 = 1.0f - (r.y - f1), wc1 = 1.0f - (c1 - r.y);
        float vg = v * (wf1 * xrow[(int)f1] + wc1 * xrow[(int)c1]);
        unsafeAtomicAdd(&y_s[(int)f0], wf0 * vg);
        unsafeAtomicAdd(&y_s[(int)c0], wc0 * vg);
    }
    __syncthreads();
    float* yrow = y + (size_t)b * DIM;
    for (int i = tid; i < DIM; i += BLOCK) atomicAdd(&yrow[i], y_s[i]);
}

extern "C" void kernel_launch(void* const* d_in, const int* in_sizes, int n_in,
                              void* d_out, int out_size, void* d_ws, size_t ws_size,
                              hipStream_t stream) {
    const float* x  = (const float*)d_in[0];
    const float* ri = (const float*)d_in[1];
    const float* rv = (const float*)d_in[2];
    float* y = (float*)d_out;

    const size_t need = (size_t)BATCH * SPLITS * DIM * sizeof(float);  // 16 MB
    dim3 grid(SPLITS, BATCH);

    if (ws_size >= need) {
        float* partials = (float*)d_ws;
        hyper_scatter_kernel<<<grid, BLOCK, 0, stream>>>(x, ri, rv, partials);
        const int n4 = BATCH * DIM / 4;  // 32768
        reduce_partials_kernel<<<n4 / 256, 256, 0, stream>>>(partials, y);
    } else {
        hipMemsetAsync(y, 0, (size_t)out_size * sizeof(float), stream);
        hyper_scatter_atomic_kernel<<<grid, BLOCK, 0, stream>>>(x, ri, rv, y);
    }
}